// Round 1
// baseline (4272.275 us; speedup 1.0000x reference)
//
#include <hip/hip_runtime.h>
#include <hip/hip_bf16.h>

#define N_NODES_C 100000
#define N_GRAPHS_C 64
#define FDIM 128

// ---------------------------------------------------------------- count (deg / graph cnt)
__global__ __launch_bounds__(256) void count_kernel(const int* __restrict__ idxs,
                                                    float* __restrict__ cnt, int n) {
    int i = blockIdx.x * blockDim.x + threadIdx.x;
    if (i < n) unsafeAtomicAdd(&cnt[idxs[i]], 1.0f);
}

// ---------------------------------------------------------------- deg -> 1/max(deg,1), in place
__global__ __launch_bounds__(256) void inv_kernel(float* __restrict__ deg, int n) {
    int i = blockIdx.x * blockDim.x + threadIdx.x;
    if (i < n) deg[i] = 1.0f / fmaxf(deg[i], 1.0f);
}

// ---------------------------------------------------------------- scatter-add of 128-float rows
// 32 lanes per edge, float4 gather + 4 scalar fp32 atomics
__global__ __launch_bounds__(256) void aggregate_kernel(const float* __restrict__ Xin,
                                                        const int* __restrict__ src,
                                                        const int* __restrict__ tgt,
                                                        float* __restrict__ Msg, int E) {
    long long idx = (long long)blockIdx.x * blockDim.x + threadIdx.x;
    int e = (int)(idx >> 5);
    int l = (int)(idx & 31);
    if (e >= E) return;
    int s = src[e];
    int t = tgt[e];
    float4 v = *(const float4*)(Xin + (size_t)s * FDIM + l * 4);
    float* dst = Msg + (size_t)t * FDIM + l * 4;
    unsafeAtomicAdd(dst + 0, v.x);
    unsafeAtomicAdd(dst + 1, v.y);
    unsafeAtomicAdd(dst + 2, v.z);
    unsafeAtomicAdd(dst + 3, v.w);
}

// ---------------------------------------------------------------- fused dual GEMM
// out[r,j] = act( inv_deg[r] * Agg[r,:]·Wl[:,j]  +  X[r,:]·Wr[:,j] + b[j] )
// Virtual K = 256: k<128 -> (Agg*inv, Wl), k>=128 -> (X, Wr).
// mode 0: relu + store to Hout (Hout may alias Agg; each block only touches its own rows)
// mode 1: no relu, mean-pool accumulate into Gsum[64][128] via run-compressed atomics.
#define GEMM_MT 64
#define GEMM_KC 16

__global__ __launch_bounds__(256) void gemm_sage(const float* __restrict__ Agg,
                                                 const float* __restrict__ X,
                                                 const float* __restrict__ Wl,
                                                 const float* __restrict__ Wr,
                                                 const float* __restrict__ bias,
                                                 const float* __restrict__ inv_deg,
                                                 float* __restrict__ Hout,
                                                 float* __restrict__ Gsum,
                                                 const int* __restrict__ batch,
                                                 int N, int mode) {
    __shared__ float sA[GEMM_KC][GEMM_MT + 4];  // +4 pad: 2-way (free) bank aliasing, keeps 16B align
    __shared__ float sW[GEMM_KC][FDIM];

    const int t = threadIdx.x;
    const int cg = t & 31;   // column group -> j0
    const int rg = t >> 5;   // row group (0..7) -> rows rg*8 .. rg*8+7
    const int j0 = cg * 4;
    const int r0 = blockIdx.x * GEMM_MT;

    float acc[8][4];
#pragma unroll
    for (int i = 0; i < 8; ++i)
#pragma unroll
        for (int c = 0; c < 4; ++c) acc[i][c] = 0.f;

    const int ra = t >> 2;        // 0..63 : row within tile this thread stages
    const int ks = (t & 3) * 4;   // 0,4,8,12 : k offset within chunk

    for (int kk = 0; kk < 2 * FDIM; kk += GEMM_KC) {
        const bool left = (kk < FDIM);
        const int kb = kk & (FDIM - 1);

        // ---- stage A chunk (64 rows x 16 k), transposed into sA[k][r]
        float4 av = make_float4(0.f, 0.f, 0.f, 0.f);
        int grow = r0 + ra;
        if (grow < N) {
            if (left) {
                av = *(const float4*)(Agg + (size_t)grow * FDIM + kb + ks);
                float s = inv_deg[grow];
                av.x *= s; av.y *= s; av.z *= s; av.w *= s;
            } else {
                av = *(const float4*)(X + (size_t)grow * FDIM + kb + ks);
            }
        }
        sA[ks + 0][ra] = av.x;
        sA[ks + 1][ra] = av.y;
        sA[ks + 2][ra] = av.z;
        sA[ks + 3][ra] = av.w;

        // ---- stage W chunk (16 k x 128 j)
        const float* Wsrc = left ? Wl : Wr;
        const int wk = t >> 5;          // 0..7
        const int wj = (t & 31) * 4;
        *(float4*)&sW[wk][wj]     = *(const float4*)(Wsrc + (size_t)(kb + wk) * FDIM + wj);
        *(float4*)&sW[wk + 8][wj] = *(const float4*)(Wsrc + (size_t)(kb + wk + 8) * FDIM + wj);

        __syncthreads();

#pragma unroll
        for (int k = 0; k < GEMM_KC; ++k) {
            float4 w = *(const float4*)&sW[k][j0];
            float4 a0 = *(const float4*)&sA[k][rg * 8];
            float4 a1 = *(const float4*)&sA[k][rg * 8 + 4];
            float a[8] = {a0.x, a0.y, a0.z, a0.w, a1.x, a1.y, a1.z, a1.w};
            float wv[4] = {w.x, w.y, w.z, w.w};
#pragma unroll
            for (int i = 0; i < 8; ++i)
#pragma unroll
                for (int c = 0; c < 4; ++c) acc[i][c] += a[i] * wv[c];
        }
        __syncthreads();
    }

    // ---- epilogue
    float4 bv = *(const float4*)&bias[j0];
    if (mode == 0) {
#pragma unroll
        for (int i = 0; i < 8; ++i) {
            int row = r0 + rg * 8 + i;
            if (row >= N) break;
            float4 o;
            o.x = fmaxf(acc[i][0] + bv.x, 0.f);
            o.y = fmaxf(acc[i][1] + bv.y, 0.f);
            o.z = fmaxf(acc[i][2] + bv.z, 0.f);
            o.w = fmaxf(acc[i][3] + bv.w, 0.f);
            *(float4*)(Hout + (size_t)row * FDIM + j0) = o;
        }
    } else {
        // pool directly: batch is sorted, so runs of equal graph id -> few atomics
        int curg = -1;
        float s0 = 0.f, s1 = 0.f, s2 = 0.f, s3 = 0.f;
#pragma unroll
        for (int i = 0; i < 8; ++i) {
            int row = r0 + rg * 8 + i;
            if (row >= N) break;
            int g = batch[row];
            if (g != curg) {
                if (curg >= 0) {
                    float* p = Gsum + (size_t)curg * FDIM + j0;
                    unsafeAtomicAdd(p + 0, s0);
                    unsafeAtomicAdd(p + 1, s1);
                    unsafeAtomicAdd(p + 2, s2);
                    unsafeAtomicAdd(p + 3, s3);
                }
                curg = g;
                s0 = s1 = s2 = s3 = 0.f;
            }
            s0 += acc[i][0] + bv.x;
            s1 += acc[i][1] + bv.y;
            s2 += acc[i][2] + bv.z;
            s3 += acc[i][3] + bv.w;
        }
        if (curg >= 0) {
            float* p = Gsum + (size_t)curg * FDIM + j0;
            unsafeAtomicAdd(p + 0, s0);
            unsafeAtomicAdd(p + 1, s1);
            unsafeAtomicAdd(p + 2, s2);
            unsafeAtomicAdd(p + 3, s3);
        }
    }
}

// ---------------------------------------------------------------- final: out = (Gsum/cnt) @ Wout + bout
__global__ __launch_bounds__(128) void final_kernel(const float* __restrict__ Gsum,
                                                    const float* __restrict__ Gcnt,
                                                    const float* __restrict__ Wout,
                                                    const float* __restrict__ bout,
                                                    float* __restrict__ out) {
    __shared__ float sg[FDIM];
    int g = blockIdx.x;
    int t = threadIdx.x;
    float inv = 1.0f / fmaxf(Gcnt[g], 1.0f);
    sg[t] = Gsum[(size_t)g * FDIM + t] * inv;
    __syncthreads();
    if (t < 10) {
        float a = bout[t];
        for (int k = 0; k < FDIM; ++k) a += sg[k] * Wout[k * 10 + t];
        out[g * 10 + t] = a;
    }
}

extern "C" void kernel_launch(void* const* d_in, const int* in_sizes, int n_in,
                              void* d_out, int out_size, void* d_ws, size_t ws_size,
                              hipStream_t stream) {
    const float* x    = (const float*)d_in[0];
    const int*   edge = (const int*)d_in[1];
    const int*   batch = (const int*)d_in[2];
    const float* W1l = (const float*)d_in[3];
    const float* b1  = (const float*)d_in[4];
    const float* W1r = (const float*)d_in[5];
    const float* W2l = (const float*)d_in[6];
    const float* b2  = (const float*)d_in[7];
    const float* W2r = (const float*)d_in[8];
    const float* W3l = (const float*)d_in[9];
    const float* b3  = (const float*)d_in[10];
    const float* W3r = (const float*)d_in[11];
    const float* Wout = (const float*)d_in[12];
    const float* bout = (const float*)d_in[13];
    float* out = (float*)d_out;

    const int N = N_NODES_C;
    const int E = in_sizes[1] / 2;
    const int* src = edge;
    const int* tgt = edge + E;

    // workspace layout (bytes)
    char* ws = (char*)d_ws;
    const size_t degOff  = 0;                       // N floats
    const size_t bufAOff = 512 * 1024;              // N*128 floats
    const size_t bufBOff = bufAOff + (size_t)N * FDIM * 4;
    const size_t gsumOff = bufBOff + (size_t)N * FDIM * 4;
    const size_t gcntOff = gsumOff + (size_t)N_GRAPHS_C * FDIM * 4;
    float* deg  = (float*)(ws + degOff);   // becomes inv_deg
    float* bufA = (float*)(ws + bufAOff);
    float* bufB = (float*)(ws + bufBOff);
    float* gsum = (float*)(ws + gsumOff);
    float* gcnt = (float*)(ws + gcntOff);

    const size_t featBytes = (size_t)N * FDIM * 4;

    // zero init
    hipMemsetAsync(deg, 0, (size_t)N * 4, stream);
    hipMemsetAsync(gsum, 0, (size_t)N_GRAPHS_C * FDIM * 4 + 256, stream);  // gsum + gcnt
    hipMemsetAsync(bufA, 0, featBytes, stream);
    hipMemsetAsync(bufB, 0, featBytes, stream);

    // degree + graph counts + inverse
    count_kernel<<<(E + 255) / 256, 256, 0, stream>>>(tgt, deg, E);
    count_kernel<<<(N + 255) / 256, 256, 0, stream>>>(batch, gcnt, N);
    inv_kernel<<<(N + 255) / 256, 256, 0, stream>>>(deg, N);

    const int aggGrid = (int)(((long long)E * 32 + 255) / 256);
    const int gemmGrid = (N + GEMM_MT - 1) / GEMM_MT;

    // ---- layer 1: agg1 -> bufA ; h1 = relu(...) in place into bufA
    aggregate_kernel<<<aggGrid, 256, 0, stream>>>(x, src, tgt, bufA, E);
    gemm_sage<<<gemmGrid, 256, 0, stream>>>(bufA, x, W1l, W1r, b1, deg, bufA, nullptr, nullptr, N, 0);

    // ---- layer 2: agg2 -> bufB ; h2 in place into bufB
    aggregate_kernel<<<aggGrid, 256, 0, stream>>>(bufA, src, tgt, bufB, E);
    gemm_sage<<<gemmGrid, 256, 0, stream>>>(bufB, bufA, W2l, W2r, b2, deg, bufB, nullptr, nullptr, N, 0);

    // ---- layer 3: agg3 -> bufA (re-zero first) ; pool directly into gsum
    hipMemsetAsync(bufA, 0, featBytes, stream);
    aggregate_kernel<<<aggGrid, 256, 0, stream>>>(bufB, src, tgt, bufA, E);
    gemm_sage<<<gemmGrid, 256, 0, stream>>>(bufA, bufB, W3l, W3r, b3, deg, nullptr, gsum, batch, N, 1);

    // ---- readout
    final_kernel<<<N_GRAPHS_C, FDIM, 0, stream>>>(gsum, gcnt, Wout, bout, out);
}

// Round 2
// 609.275 us; speedup vs baseline: 7.0121x; 7.0121x over previous
//
#include <hip/hip_runtime.h>
#include <hip/hip_bf16.h>

#define N_NODES_C 100000
#define N_GRAPHS_C 64
#define FDIM 128

// ---------------------------------------------------------------- int histogram (degree)
__global__ __launch_bounds__(256) void hist_kernel(const int* __restrict__ idxs,
                                                   int* __restrict__ cnt, int n) {
    int i = blockIdx.x * blockDim.x + threadIdx.x;
    if (i < n) atomicAdd(&cnt[idxs[i]], 1);
}

// ---------------------------------------------------------------- exclusive scan (1024 elems/block)
__global__ __launch_bounds__(256) void scan_block(const int* __restrict__ deg,
                                                  int* __restrict__ out,
                                                  int* __restrict__ bsum, int n) {
    __shared__ int ts[256];
    const int t = threadIdx.x;
    const int base = blockIdx.x * 1024 + t * 4;
    int4 v = make_int4(0, 0, 0, 0);
    if (base + 3 < n) v = *(const int4*)(deg + base);
    else {
        if (base + 0 < n) v.x = deg[base + 0];
        if (base + 1 < n) v.y = deg[base + 1];
        if (base + 2 < n) v.z = deg[base + 2];
        if (base + 3 < n) v.w = deg[base + 3];
    }
    int s0 = v.x, s1 = s0 + v.y, s2 = s1 + v.z, s3 = s2 + v.w;
    ts[t] = s3;
    __syncthreads();
    for (int off = 1; off < 256; off <<= 1) {
        int val = (t >= off) ? ts[t - off] : 0;
        __syncthreads();
        ts[t] += val;
        __syncthreads();
    }
    int excl = (t > 0) ? ts[t - 1] : 0;
    int4 o = make_int4(excl, excl + s0, excl + s1, excl + s2);
    if (base + 3 < n) *(int4*)(out + base) = o;
    else {
        if (base + 0 < n) out[base + 0] = o.x;
        if (base + 1 < n) out[base + 1] = o.y;
        if (base + 2 < n) out[base + 2] = o.z;
        if (base + 3 < n) out[base + 3] = o.w;
    }
    if (t == 255) bsum[blockIdx.x] = ts[255];
}

__global__ __launch_bounds__(256) void scan_sums(int* __restrict__ bsum, int nb) {
    __shared__ int s[256];
    const int t = threadIdx.x;
    s[t] = (t < nb) ? bsum[t] : 0;
    __syncthreads();
    for (int off = 1; off < 256; off <<= 1) {
        int val = (t >= off) ? s[t - off] : 0;
        __syncthreads();
        s[t] += val;
        __syncthreads();
    }
    if (t < nb) bsum[t] = (t > 0) ? s[t - 1] : 0;  // exclusive
}

__global__ __launch_bounds__(256) void scan_add(int* __restrict__ out,
                                                const int* __restrict__ bsum,
                                                int n, int total) {
    int i = blockIdx.x * 256 + threadIdx.x;
    if (i < n) out[i] += bsum[i >> 10];
    if (i == 0) out[n] = total;
}

// ---------------------------------------------------------------- CSR scatter (by target)
__global__ __launch_bounds__(256) void scatter_kernel(const int* __restrict__ src,
                                                      const int* __restrict__ tgt,
                                                      const int* __restrict__ rowstart,
                                                      int* __restrict__ cursor,
                                                      int* __restrict__ csr, int E) {
    int e = blockIdx.x * 256 + threadIdx.x;
    if (e < E) {
        int t = tgt[e];
        int p = rowstart[t] + atomicAdd(&cursor[t], 1);
        csr[p] = src[e];
    }
}

// ---------------------------------------------------------------- inv_deg from int degree
__global__ __launch_bounds__(256) void inv_kernel(const int* __restrict__ degi,
                                                  float* __restrict__ invd, int n) {
    int i = blockIdx.x * blockDim.x + threadIdx.x;
    if (i < n) invd[i] = 1.0f / (float)max(degi[i], 1);
}

// ---------------------------------------------------------------- graph node counts (batch sorted)
__global__ __launch_bounds__(64) void graph_cnt_kernel(const int* __restrict__ batch,
                                                       float* __restrict__ gcnt, int n) {
    int g = threadIdx.x;  // 0..63
    int lo = 0, hi = n;
    while (lo < hi) { int m = (lo + hi) >> 1; if (batch[m] < g) lo = m + 1; else hi = m; }
    int lb = lo;
    lo = 0; hi = n;
    while (lo < hi) { int m = (lo + hi) >> 1; if (batch[m] < g + 1) lo = m + 1; else hi = m; }
    gcnt[g] = (float)(lo - lb);
}

// ---------------------------------------------------------------- CSR mean-aggregate
// one wave per node; lane owns 2 features; indices prefetched + shfl-broadcast
__global__ __launch_bounds__(256) void agg_csr(const float* __restrict__ Xin,
                                               const int* __restrict__ csr,
                                               const int* __restrict__ rowstart,
                                               const float* __restrict__ invd,
                                               float* __restrict__ Agg, int N) {
    int node = (blockIdx.x << 2) + (threadIdx.x >> 6);
    if (node >= N) return;
    int lane = threadIdx.x & 63;
    int beg = rowstart[node];
    int end = rowstart[node + 1];
    float2 acc = make_float2(0.f, 0.f);
    for (int b = beg; b < end; b += 64) {
        int cnt = min(64, end - b);
        int myi = (lane < cnt) ? csr[b + lane] : 0;
        for (int k = 0; k < cnt; ++k) {
            int s = __shfl(myi, k);
            float2 v = *(const float2*)(Xin + (size_t)s * FDIM + lane * 2);
            acc.x += v.x;
            acc.y += v.y;
        }
    }
    float sc = invd[node];
    *(float2*)(Agg + (size_t)node * FDIM + lane * 2) = make_float2(acc.x * sc, acc.y * sc);
}

// ---------------------------------------------------------------- fused dual GEMM
// out[r,j] = act( Agg[r,:]·Wl[:,j] + X[r,:]·Wr[:,j] + b[j] )   (Agg pre-scaled by inv_deg)
#define GEMM_MT 64
#define GEMM_KC 16

__global__ __launch_bounds__(256) void gemm_sage(const float* __restrict__ Agg,
                                                 const float* __restrict__ X,
                                                 const float* __restrict__ Wl,
                                                 const float* __restrict__ Wr,
                                                 const float* __restrict__ bias,
                                                 float* __restrict__ Hout,
                                                 float* __restrict__ Gsum,
                                                 const int* __restrict__ batch,
                                                 int N, int mode) {
    __shared__ float sA[GEMM_KC][GEMM_MT + 4];
    __shared__ float sW[GEMM_KC][FDIM];

    const int t = threadIdx.x;
    const int cg = t & 31;
    const int rg = t >> 5;
    const int j0 = cg * 4;
    const int r0 = blockIdx.x * GEMM_MT;

    float acc[8][4];
#pragma unroll
    for (int i = 0; i < 8; ++i)
#pragma unroll
        for (int c = 0; c < 4; ++c) acc[i][c] = 0.f;

    const int ra = t >> 2;
    const int ks = (t & 3) * 4;

    for (int kk = 0; kk < 2 * FDIM; kk += GEMM_KC) {
        const bool left = (kk < FDIM);
        const int kb = kk & (FDIM - 1);

        float4 av = make_float4(0.f, 0.f, 0.f, 0.f);
        int grow = r0 + ra;
        if (grow < N) {
            const float* Asrc = left ? Agg : X;
            av = *(const float4*)(Asrc + (size_t)grow * FDIM + kb + ks);
        }
        sA[ks + 0][ra] = av.x;
        sA[ks + 1][ra] = av.y;
        sA[ks + 2][ra] = av.z;
        sA[ks + 3][ra] = av.w;

        const float* Wsrc = left ? Wl : Wr;
        const int wk = t >> 5;
        const int wj = (t & 31) * 4;
        *(float4*)&sW[wk][wj]     = *(const float4*)(Wsrc + (size_t)(kb + wk) * FDIM + wj);
        *(float4*)&sW[wk + 8][wj] = *(const float4*)(Wsrc + (size_t)(kb + wk + 8) * FDIM + wj);

        __syncthreads();

#pragma unroll
        for (int k = 0; k < GEMM_KC; ++k) {
            float4 w = *(const float4*)&sW[k][j0];
            float4 a0 = *(const float4*)&sA[k][rg * 8];
            float4 a1 = *(const float4*)&sA[k][rg * 8 + 4];
            float a[8] = {a0.x, a0.y, a0.z, a0.w, a1.x, a1.y, a1.z, a1.w};
            float wv[4] = {w.x, w.y, w.z, w.w};
#pragma unroll
            for (int i = 0; i < 8; ++i)
#pragma unroll
                for (int c = 0; c < 4; ++c) acc[i][c] += a[i] * wv[c];
        }
        __syncthreads();
    }

    float4 bv = *(const float4*)&bias[j0];
    if (mode == 0) {
#pragma unroll
        for (int i = 0; i < 8; ++i) {
            int row = r0 + rg * 8 + i;
            if (row >= N) break;
            float4 o;
            o.x = fmaxf(acc[i][0] + bv.x, 0.f);
            o.y = fmaxf(acc[i][1] + bv.y, 0.f);
            o.z = fmaxf(acc[i][2] + bv.z, 0.f);
            o.w = fmaxf(acc[i][3] + bv.w, 0.f);
            *(float4*)(Hout + (size_t)row * FDIM + j0) = o;
        }
    } else {
        int curg = -1;
        float s0 = 0.f, s1 = 0.f, s2 = 0.f, s3 = 0.f;
#pragma unroll
        for (int i = 0; i < 8; ++i) {
            int row = r0 + rg * 8 + i;
            if (row >= N) break;
            int g = batch[row];
            if (g != curg) {
                if (curg >= 0) {
                    float* p = Gsum + (size_t)curg * FDIM + j0;
                    unsafeAtomicAdd(p + 0, s0);
                    unsafeAtomicAdd(p + 1, s1);
                    unsafeAtomicAdd(p + 2, s2);
                    unsafeAtomicAdd(p + 3, s3);
                }
                curg = g;
                s0 = s1 = s2 = s3 = 0.f;
            }
            s0 += acc[i][0] + bv.x;
            s1 += acc[i][1] + bv.y;
            s2 += acc[i][2] + bv.z;
            s3 += acc[i][3] + bv.w;
        }
        if (curg >= 0) {
            float* p = Gsum + (size_t)curg * FDIM + j0;
            unsafeAtomicAdd(p + 0, s0);
            unsafeAtomicAdd(p + 1, s1);
            unsafeAtomicAdd(p + 2, s2);
            unsafeAtomicAdd(p + 3, s3);
        }
    }
}

// ---------------------------------------------------------------- final: out = (Gsum/cnt) @ Wout + bout
__global__ __launch_bounds__(128) void final_kernel(const float* __restrict__ Gsum,
                                                    const float* __restrict__ Gcnt,
                                                    const float* __restrict__ Wout,
                                                    const float* __restrict__ bout,
                                                    float* __restrict__ out) {
    __shared__ float sg[FDIM];
    int g = blockIdx.x;
    int t = threadIdx.x;
    float inv = 1.0f / fmaxf(Gcnt[g], 1.0f);
    sg[t] = Gsum[(size_t)g * FDIM + t] * inv;
    __syncthreads();
    if (t < 10) {
        float a = bout[t];
        for (int k = 0; k < FDIM; ++k) a += sg[k] * Wout[k * 10 + t];
        out[g * 10 + t] = a;
    }
}

extern "C" void kernel_launch(void* const* d_in, const int* in_sizes, int n_in,
                              void* d_out, int out_size, void* d_ws, size_t ws_size,
                              hipStream_t stream) {
    const float* x    = (const float*)d_in[0];
    const int*   edge = (const int*)d_in[1];
    const int*   batch = (const int*)d_in[2];
    const float* W1l = (const float*)d_in[3];
    const float* b1  = (const float*)d_in[4];
    const float* W1r = (const float*)d_in[5];
    const float* W2l = (const float*)d_in[6];
    const float* b2  = (const float*)d_in[7];
    const float* W2r = (const float*)d_in[8];
    const float* W3l = (const float*)d_in[9];
    const float* b3  = (const float*)d_in[10];
    const float* W3r = (const float*)d_in[11];
    const float* Wout = (const float*)d_in[12];
    const float* bout = (const float*)d_in[13];
    float* out = (float*)d_out;

    const int N = N_NODES_C;
    const int E = in_sizes[1] / 2;
    const int* src = edge;
    const int* tgt = edge + E;

    // ---- workspace layout (256B-aligned chunks)
    char* ws = (char*)d_ws;
    size_t off = 0;
    auto carve = [&](size_t bytes) { char* p = ws + off; off += (bytes + 255) & ~(size_t)255; return p; };
    int*   degi = (int*)carve((size_t)N * 4);
    int*   rs   = (int*)carve((size_t)(N + 1) * 4);
    int*   cur  = (int*)carve((size_t)N * 4);
    int*   bsum = (int*)carve(1024);
    float* invd = (float*)carve((size_t)N * 4);
    float* gsum = (float*)carve((size_t)N_GRAPHS_C * FDIM * 4);
    float* gcnt = (float*)carve((size_t)N_GRAPHS_C * 4);
    int*   csr  = (int*)carve((size_t)E * 4);
    float* bufA = (float*)carve((size_t)N * FDIM * 4);
    float* bufB = (float*)carve((size_t)N * FDIM * 4);

    // ---- zero init (small buffers only)
    hipMemsetAsync(degi, 0, (size_t)N * 4, stream);
    hipMemsetAsync(cur, 0, (size_t)N * 4, stream);
    hipMemsetAsync(gsum, 0, (size_t)N_GRAPHS_C * FDIM * 4, stream);

    // ---- CSR build
    hist_kernel<<<(E + 255) / 256, 256, 0, stream>>>(tgt, degi, E);
    const int NB = (N + 1023) / 1024;
    scan_block<<<NB, 256, 0, stream>>>(degi, rs, bsum, N);
    scan_sums<<<1, 256, 0, stream>>>(bsum, NB);
    scan_add<<<(N + 255) / 256, 256, 0, stream>>>(rs, bsum, N, E);
    inv_kernel<<<(N + 255) / 256, 256, 0, stream>>>(degi, invd, N);
    graph_cnt_kernel<<<1, 64, 0, stream>>>(batch, gcnt, N);
    scatter_kernel<<<(E + 255) / 256, 256, 0, stream>>>(src, tgt, rs, cur, csr, E);

    const int aggGrid = (N + 3) / 4;
    const int gemmGrid = (N + GEMM_MT - 1) / GEMM_MT;

    // ---- layer 1
    agg_csr<<<aggGrid, 256, 0, stream>>>(x, csr, rs, invd, bufA, N);
    gemm_sage<<<gemmGrid, 256, 0, stream>>>(bufA, x, W1l, W1r, b1, bufA, nullptr, nullptr, N, 0);

    // ---- layer 2
    agg_csr<<<aggGrid, 256, 0, stream>>>(bufA, csr, rs, invd, bufB, N);
    gemm_sage<<<gemmGrid, 256, 0, stream>>>(bufB, bufA, W2l, W2r, b2, bufB, nullptr, nullptr, N, 0);

    // ---- layer 3 (pool directly)
    agg_csr<<<aggGrid, 256, 0, stream>>>(bufB, csr, rs, invd, bufA, N);
    gemm_sage<<<gemmGrid, 256, 0, stream>>>(bufA, bufB, W3l, W3r, b3, nullptr, gsum, batch, N, 1);

    // ---- readout
    final_kernel<<<N_GRAPHS_C, FDIM, 0, stream>>>(gsum, gcnt, Wout, bout, out);
}

// Round 3
// 379.211 us; speedup vs baseline: 11.2662x; 1.6067x over previous
//
#include <hip/hip_runtime.h>
#include <hip/hip_bf16.h>

#define N_NODES_C 100000
#define N_GRAPHS_C 64
#define FDIM 128

typedef __attribute__((ext_vector_type(8))) short short8v;
typedef __attribute__((ext_vector_type(4))) float f32x4;
typedef __attribute__((ext_vector_type(4))) unsigned short us4;

__device__ __forceinline__ unsigned short f2bf(float f) {
    union { float f; unsigned u; } v; v.f = f;
    unsigned r = v.u + 0x7fffu + ((v.u >> 16) & 1u);   // RNE
    return (unsigned short)(r >> 16);
}
__device__ __forceinline__ float bf2f(unsigned short h) {
    union { unsigned u; float f; } v; v.u = ((unsigned)h) << 16; return v.f;
}

// ---------------------------------------------------------------- int histogram (degree)
__global__ __launch_bounds__(256) void hist_kernel(const int* __restrict__ idxs,
                                                   int* __restrict__ cnt, int n) {
    int i = blockIdx.x * blockDim.x + threadIdx.x;
    if (i < n) atomicAdd(&cnt[idxs[i]], 1);
}

// ---------------------------------------------------------------- exclusive scan (1024/block)
__global__ __launch_bounds__(256) void scan_block(const int* __restrict__ deg,
                                                  int* __restrict__ out,
                                                  int* __restrict__ bsum, int n) {
    __shared__ int ts[256];
    const int t = threadIdx.x;
    const int base = blockIdx.x * 1024 + t * 4;
    int4 v = make_int4(0, 0, 0, 0);
    if (base + 3 < n) v = *(const int4*)(deg + base);
    else {
        if (base + 0 < n) v.x = deg[base + 0];
        if (base + 1 < n) v.y = deg[base + 1];
        if (base + 2 < n) v.z = deg[base + 2];
        if (base + 3 < n) v.w = deg[base + 3];
    }
    int s0 = v.x, s1 = s0 + v.y, s2 = s1 + v.z, s3 = s2 + v.w;
    ts[t] = s3;
    __syncthreads();
    for (int off = 1; off < 256; off <<= 1) {
        int val = (t >= off) ? ts[t - off] : 0;
        __syncthreads();
        ts[t] += val;
        __syncthreads();
    }
    int excl = (t > 0) ? ts[t - 1] : 0;
    int4 o = make_int4(excl, excl + s0, excl + s1, excl + s2);
    if (base + 3 < n) *(int4*)(out + base) = o;
    else {
        if (base + 0 < n) out[base + 0] = o.x;
        if (base + 1 < n) out[base + 1] = o.y;
        if (base + 2 < n) out[base + 2] = o.z;
        if (base + 3 < n) out[base + 3] = o.w;
    }
    if (t == 255) bsum[blockIdx.x] = ts[255];
}

__global__ __launch_bounds__(256) void scan_sums(int* __restrict__ bsum, int nb) {
    __shared__ int s[256];
    const int t = threadIdx.x;
    s[t] = (t < nb) ? bsum[t] : 0;
    __syncthreads();
    for (int off = 1; off < 256; off <<= 1) {
        int val = (t >= off) ? s[t - off] : 0;
        __syncthreads();
        s[t] += val;
        __syncthreads();
    }
    if (t < nb) bsum[t] = (t > 0) ? s[t - 1] : 0;
}

__global__ __launch_bounds__(256) void scan_add(int* __restrict__ out,
                                                const int* __restrict__ bsum,
                                                int n, int total) {
    int i = blockIdx.x * 256 + threadIdx.x;
    if (i < n) out[i] += bsum[i >> 10];
    if (i == 0) out[n] = total;
}

// ---------------------------------------------------------------- CSR scatter (by target)
__global__ __launch_bounds__(256) void scatter_kernel(const int* __restrict__ src,
                                                      const int* __restrict__ tgt,
                                                      const int* __restrict__ rowstart,
                                                      int* __restrict__ cursor,
                                                      int* __restrict__ csr, int E) {
    int e = blockIdx.x * 256 + threadIdx.x;
    if (e < E) {
        int t = tgt[e];
        int p = rowstart[t] + atomicAdd(&cursor[t], 1);
        csr[p] = src[e];
    }
}

// ---------------------------------------------------------------- inv_deg
__global__ __launch_bounds__(256) void inv_kernel(const int* __restrict__ degi,
                                                  float* __restrict__ invd, int n) {
    int i = blockIdx.x * blockDim.x + threadIdx.x;
    if (i < n) invd[i] = 1.0f / (float)max(degi[i], 1);
}

// ---------------------------------------------------------------- graph boundaries (batch sorted)
__global__ __launch_bounds__(64) void graph_cnt_kernel(const int* __restrict__ batch,
                                                       int* __restrict__ gstart,
                                                       float* __restrict__ gcnt, int n) {
    int g = threadIdx.x;  // 0..63
    int lo = 0, hi = n;
    while (lo < hi) { int m = (lo + hi) >> 1; if (batch[m] < g) lo = m + 1; else hi = m; }
    int lb = lo;
    lo = 0; hi = n;
    while (lo < hi) { int m = (lo + hi) >> 1; if (batch[m] < g + 1) lo = m + 1; else hi = m; }
    gstart[g] = lb;
    gcnt[g] = (float)(lo - lb);
    if (g == 0) gstart[64] = n;
}

// ---------------------------------------------------------------- fp32 -> bf16 convert
__global__ __launch_bounds__(256) void conv_bf16(const float* __restrict__ in,
                                                 unsigned short* __restrict__ out, int n4) {
    int i = blockIdx.x * 256 + threadIdx.x;
    if (i < n4) {
        float4 v = *(const float4*)(in + (size_t)i * 4);
        us4 o; o.x = f2bf(v.x); o.y = f2bf(v.y); o.z = f2bf(v.z); o.w = f2bf(v.w);
        *(us4*)(out + (size_t)i * 4) = o;
    }
}

// ---------------------------------------------------------------- weight prep: fragment-ordered Wt hi/lo
// chunk c (0..63): nf=c>>3, ks=c&7 ; elem i (0..511): l=i>>3, e=i&7
// j = nf*16 + (l&15) ; k = ks*32 + (l>>4)*8 + e ; W = k<128 ? Wl[k][j] : Wr[k-128][j]
__global__ __launch_bounds__(256) void prep_w(const float* __restrict__ Wl,
                                              const float* __restrict__ Wr,
                                              unsigned short* __restrict__ outHi,
                                              unsigned short* __restrict__ outLo) {
    int id = blockIdx.x * 256 + threadIdx.x;  // 0..32767
    int c = id >> 9, i = id & 511;
    int l = i >> 3, e = i & 7;
    int j = (c >> 3) * 16 + (l & 15);
    int k = (c & 7) * 32 + ((l >> 4) << 3) + e;
    float w = (k < 128) ? Wl[k * 128 + j] : Wr[(k - 128) * 128 + j];
    unsigned short hi = f2bf(w);
    float lo = w - bf2f(hi);
    outHi[id] = hi;
    outLo[id] = f2bf(lo);
}

// ---------------------------------------------------------------- CSR mean-aggregate (bf16 in/out)
__global__ __launch_bounds__(256) void agg_bf16(const unsigned short* __restrict__ Xin,
                                                const int* __restrict__ csr,
                                                const int* __restrict__ rowstart,
                                                const float* __restrict__ invd,
                                                unsigned short* __restrict__ Agg, int N) {
    int node = (blockIdx.x << 2) + (threadIdx.x >> 6);
    if (node >= N) return;
    int lane = threadIdx.x & 63;
    int beg = rowstart[node];
    int end = rowstart[node + 1];
    float a0 = 0.f, a1 = 0.f;
    for (int b = beg; b < end; b += 64) {
        int cnt = min(64, end - b);
        int myi = (lane < cnt) ? csr[b + lane] : 0;
        for (int k = 0; k < cnt; ++k) {
            int s = __shfl(myi, k);
            unsigned u = *(const unsigned*)(Xin + ((size_t)s << 7) + lane * 2);
            a0 += bf2f((unsigned short)u);
            a1 += bf2f((unsigned short)(u >> 16));
        }
    }
    float sc = invd[node];
    unsigned o = ((unsigned)f2bf(a1 * sc) << 16) | (unsigned)f2bf(a0 * sc);
    *(unsigned*)(Agg + ((size_t)node << 7) + lane * 2) = o;
}

// ---------------------------------------------------------------- MFMA dual GEMM, split-precision W
// H[r,:] = relu( [Agg(r)|X(r)] @ (Whi+Wlo) + b ),  virtual K=256, bf16 in, bf16 out
// 512 thr = 8 waves; wave owns 32 rows x 128 cols (2 m-frags x 8 n-frags, 16x16x32 MFMA)
__global__ __launch_bounds__(512) void gemm_mfma(const unsigned short* __restrict__ Agg,
                                                 const unsigned short* __restrict__ Xop,
                                                 const unsigned short* __restrict__ WtHi,
                                                 const unsigned short* __restrict__ WtLo,
                                                 const float* __restrict__ bias,
                                                 unsigned short* __restrict__ Hout, int N) {
    __shared__ unsigned short wlds[2][32][512];   // 64 KiB: [hi/lo][nf*4+ks4][frag elems]

    const int t = threadIdx.x;
    const int wave = t >> 6;
    const int l = t & 63;
    const int rw = blockIdx.x * 256 + wave * 32;
    const int lrow = l & 15;
    const int lk = (l >> 4) << 3;

    f32x4 acc[2][8];
#pragma unroll
    for (int m = 0; m < 2; ++m)
#pragma unroll
        for (int nf = 0; nf < 8; ++nf) acc[m][nf] = (f32x4)(0.f);

    for (int khalf = 0; khalf < 2; ++khalf) {
        __syncthreads();
        // stage this k-half's W fragments: 32 chunks x 512 us x {hi,lo} = 64 KiB
#pragma unroll
        for (int rep = 0; rep < 8; ++rep) {
            int u = rep * 4096 + t * 8;
            int h = u >> 14;
            int w = u & 16383;
            int cl = w >> 9;
            int off = w & 511;
            int gc = (cl >> 2) * 8 + khalf * 4 + (cl & 3);
            const unsigned short* srcp = (h ? WtLo : WtHi) + gc * 512 + off;
            *(short8v*)&wlds[h][cl][off] = *(const short8v*)srcp;
        }
        __syncthreads();

        const unsigned short* Asrc = khalf ? Xop : Agg;
#pragma unroll
        for (int ks4 = 0; ks4 < 4; ++ks4) {
            short8v af[2];
#pragma unroll
            for (int m = 0; m < 2; ++m) {
                int row = rw + m * 16 + lrow;
                if (row >= N) row = N - 1;  // clamp: only pollutes discarded rows
                af[m] = *(const short8v*)(Asrc + ((size_t)row << 7) + ks4 * 32 + lk);
            }
#pragma unroll
            for (int nf = 0; nf < 8; ++nf) {
                int cl = nf * 4 + ks4;
                short8v bh = *(const short8v*)&wlds[0][cl][l * 8];
                short8v bl = *(const short8v*)&wlds[1][cl][l * 8];
#pragma unroll
                for (int m = 0; m < 2; ++m) {
                    acc[m][nf] = __builtin_amdgcn_mfma_f32_16x16x32_bf16(af[m], bh, acc[m][nf], 0, 0, 0);
                    acc[m][nf] = __builtin_amdgcn_mfma_f32_16x16x32_bf16(af[m], bl, acc[m][nf], 0, 0, 0);
                }
            }
        }
    }

    // epilogue: D[row=(l>>4)*4+r][col=l&15] per frag ; bias + relu + bf16 store
    const int rbase = (l >> 4) << 2;
#pragma unroll
    for (int nf = 0; nf < 8; ++nf) {
        float bj = bias[nf * 16 + (l & 15)];
#pragma unroll
        for (int m = 0; m < 2; ++m) {
#pragma unroll
            for (int r = 0; r < 4; ++r) {
                int row = rw + m * 16 + rbase + r;
                if (row < N) {
                    float v = fmaxf(acc[m][nf][r] + bj, 0.f);
                    Hout[((size_t)row << 7) + nf * 16 + (l & 15)] = f2bf(v);
                }
            }
        }
    }
}

// ---------------------------------------------------------------- segment-mean pool of agg3 & h2
__global__ __launch_bounds__(256) void pool_kernel(const unsigned short* __restrict__ A3,
                                                   const unsigned short* __restrict__ H2,
                                                   const int* __restrict__ gstart,
                                                   float* __restrict__ pa,
                                                   float* __restrict__ ph) {
    int g = blockIdx.x >> 2, q = blockIdx.x & 3;
    int s = gstart[g], e = gstart[g + 1];
    int len = e - s;
    int cs = s + (len * q) / 4;
    int ce = s + (len * (q + 1)) / 4;
    int t = threadIdx.x;
    int cp = t & 63;   // column pair
    int rp = t >> 6;   // 0..3 row phase
    float sa0 = 0, sa1 = 0, sh0 = 0, sh1 = 0;
    for (int r = cs + rp; r < ce; r += 4) {
        unsigned ua = *(const unsigned*)(A3 + ((size_t)r << 7) + cp * 2);
        unsigned uh = *(const unsigned*)(H2 + ((size_t)r << 7) + cp * 2);
        sa0 += bf2f((unsigned short)ua); sa1 += bf2f((unsigned short)(ua >> 16));
        sh0 += bf2f((unsigned short)uh); sh1 += bf2f((unsigned short)(uh >> 16));
    }
    __shared__ float red[4][4][64];
    red[rp][0][cp] = sa0; red[rp][1][cp] = sa1;
    red[rp][2][cp] = sh0; red[rp][3][cp] = sh1;
    __syncthreads();
    if (rp == 0) {
        float ra0 = red[0][0][cp] + red[1][0][cp] + red[2][0][cp] + red[3][0][cp];
        float ra1 = red[0][1][cp] + red[1][1][cp] + red[2][1][cp] + red[3][1][cp];
        float rh0 = red[0][2][cp] + red[1][2][cp] + red[2][2][cp] + red[3][2][cp];
        float rh1 = red[0][3][cp] + red[1][3][cp] + red[2][3][cp] + red[3][3][cp];
        unsafeAtomicAdd(&pa[g * 128 + cp * 2 + 0], ra0);
        unsafeAtomicAdd(&pa[g * 128 + cp * 2 + 1], ra1);
        unsafeAtomicAdd(&ph[g * 128 + cp * 2 + 0], rh0);
        unsafeAtomicAdd(&ph[g * 128 + cp * 2 + 1], rh1);
    }
}

// ---------------------------------------------------------------- fused layer3 + readout (fp32)
__global__ __launch_bounds__(128) void final_fused(const float* __restrict__ pa,
                                                   const float* __restrict__ ph,
                                                   const float* __restrict__ gcnt,
                                                   const float* __restrict__ W3l,
                                                   const float* __restrict__ W3r,
                                                   const float* __restrict__ b3,
                                                   const float* __restrict__ Wout,
                                                   const float* __restrict__ bout,
                                                   float* __restrict__ out) {
    __shared__ float sA[FDIM], sH[FDIM], sT[FDIM];
    int g = blockIdx.x;
    int j = threadIdx.x;
    float inv = 1.0f / fmaxf(gcnt[g], 1.0f);
    sA[j] = pa[g * FDIM + j] * inv;
    sH[j] = ph[g * FDIM + j] * inv;
    __syncthreads();
    float acc = b3[j];
    for (int c = 0; c < FDIM; ++c)
        acc += sA[c] * W3l[c * FDIM + j] + sH[c] * W3r[c * FDIM + j];
    sT[j] = acc;   // no relu on layer 3
    __syncthreads();
    if (j < 10) {
        float o = bout[j];
        for (int c = 0; c < FDIM; ++c) o += sT[c] * Wout[c * 10 + j];
        out[g * 10 + j] = o;
    }
}

extern "C" void kernel_launch(void* const* d_in, const int* in_sizes, int n_in,
                              void* d_out, int out_size, void* d_ws, size_t ws_size,
                              hipStream_t stream) {
    const float* x     = (const float*)d_in[0];
    const int*   edge  = (const int*)d_in[1];
    const int*   batch = (const int*)d_in[2];
    const float* W1l = (const float*)d_in[3];
    const float* b1  = (const float*)d_in[4];
    const float* W1r = (const float*)d_in[5];
    const float* W2l = (const float*)d_in[6];
    const float* b2  = (const float*)d_in[7];
    const float* W2r = (const float*)d_in[8];
    const float* W3l = (const float*)d_in[9];
    const float* b3  = (const float*)d_in[10];
    const float* W3r = (const float*)d_in[11];
    const float* Wout = (const float*)d_in[12];
    const float* bout = (const float*)d_in[13];
    float* out = (float*)d_out;

    const int N = N_NODES_C;
    const int E = in_sizes[1] / 2;
    const int* src = edge;
    const int* tgt = edge + E;

    // ---- workspace layout
    char* ws = (char*)d_ws;
    size_t off = 0;
    auto carve = [&](size_t bytes) { char* p = ws + off; off += (bytes + 255) & ~(size_t)255; return p; };
    int*   degi = (int*)carve((size_t)N * 4);
    int*   rs   = (int*)carve((size_t)(N + 1) * 4);
    int*   cur  = (int*)carve((size_t)N * 4);
    int*   bsum = (int*)carve(1024);
    float* invd = (float*)carve((size_t)N * 4);
    int*   gstart = (int*)carve(65 * 4);
    float* gcnt = (float*)carve(64 * 4);
    float* pa   = (float*)carve((size_t)N_GRAPHS_C * FDIM * 4);
    float* ph   = (float*)carve((size_t)N_GRAPHS_C * FDIM * 4);
    unsigned short* wt1hi = (unsigned short*)carve(32768 * 2);
    unsigned short* wt1lo = (unsigned short*)carve(32768 * 2);
    unsigned short* wt2hi = (unsigned short*)carve(32768 * 2);
    unsigned short* wt2lo = (unsigned short*)carve(32768 * 2);
    int*   csr  = (int*)carve((size_t)E * 4);
    unsigned short* B0 = (unsigned short*)carve((size_t)N * FDIM * 2);
    unsigned short* B1 = (unsigned short*)carve((size_t)N * FDIM * 2);
    unsigned short* B2 = (unsigned short*)carve((size_t)N * FDIM * 2);

    // ---- zero init
    hipMemsetAsync(degi, 0, (size_t)N * 4, stream);
    hipMemsetAsync(cur, 0, (size_t)N * 4, stream);
    hipMemsetAsync(pa, 0, (size_t)N_GRAPHS_C * FDIM * 4, stream);
    hipMemsetAsync(ph, 0, (size_t)N_GRAPHS_C * FDIM * 4, stream);

    // ---- CSR build + degree
    hist_kernel<<<(E + 255) / 256, 256, 0, stream>>>(tgt, degi, E);
    const int NB = (N + 1023) / 1024;
    scan_block<<<NB, 256, 0, stream>>>(degi, rs, bsum, N);
    scan_sums<<<1, 256, 0, stream>>>(bsum, NB);
    scan_add<<<(N + 255) / 256, 256, 0, stream>>>(rs, bsum, N, E);
    inv_kernel<<<(N + 255) / 256, 256, 0, stream>>>(degi, invd, N);
    graph_cnt_kernel<<<1, 64, 0, stream>>>(batch, gstart, gcnt, N);
    scatter_kernel<<<(E + 255) / 256, 256, 0, stream>>>(src, tgt, rs, cur, csr, E);

    // ---- conversions / weight prep
    conv_bf16<<<(N * FDIM / 4 + 255) / 256, 256, 0, stream>>>(x, B0, N * FDIM / 4);
    prep_w<<<128, 256, 0, stream>>>(W1l, W1r, wt1hi, wt1lo);
    prep_w<<<128, 256, 0, stream>>>(W2l, W2r, wt2hi, wt2lo);

    const int aggGrid = (N + 3) / 4;
    const int gemmGrid = (N + 255) / 256;

    // ---- layer 1: agg1 -> B1 ; h1 = relu([B1|B0]@Wt1+b1) -> B2
    agg_bf16<<<aggGrid, 256, 0, stream>>>(B0, csr, rs, invd, B1, N);
    gemm_mfma<<<gemmGrid, 512, 0, stream>>>(B1, B0, wt1hi, wt1lo, b1, B2, N);

    // ---- layer 2: agg2 -> B1 ; h2 = relu([B1|B2]@Wt2+b2) -> B0
    agg_bf16<<<aggGrid, 256, 0, stream>>>(B2, csr, rs, invd, B1, N);
    gemm_mfma<<<gemmGrid, 512, 0, stream>>>(B1, B2, wt2hi, wt2lo, b2, B0, N);

    // ---- layer 3 folded through pooling: agg3 -> B1 ; pool agg3 & h2
    agg_bf16<<<aggGrid, 256, 0, stream>>>(B0, csr, rs, invd, B1, N);
    pool_kernel<<<N_GRAPHS_C * 4, 256, 0, stream>>>(B1, B0, gstart, pa, ph);

    // ---- layer-3 GEMM (64 rows) + readout, full fp32
    final_fused<<<N_GRAPHS_C, 128, 0, stream>>>(pa, ph, gcnt, W3l, W3r, b3, Wout, bout, out);
}

// Round 4
// 354.894 us; speedup vs baseline: 12.0382x; 1.0685x over previous
//
#include <hip/hip_runtime.h>
#include <hip/hip_bf16.h>

#define N_NODES_C 100000
#define N_GRAPHS_C 64
#define FDIM 128

typedef __attribute__((ext_vector_type(8))) short short8v;
typedef __attribute__((ext_vector_type(4))) float f32x4;
typedef __attribute__((ext_vector_type(4))) unsigned short us4;

__device__ __forceinline__ unsigned short f2bf(float f) {
    union { float f; unsigned u; } v; v.f = f;
    unsigned r = v.u + 0x7fffu + ((v.u >> 16) & 1u);   // RNE
    return (unsigned short)(r >> 16);
}
__device__ __forceinline__ float bf2f(unsigned short h) {
    union { unsigned u; float f; } v; v.u = ((unsigned)h) << 16; return v.f;
}
__device__ __forceinline__ float bflo(unsigned u) {   // low bf16 of a u32
    union { unsigned u; float f; } v; v.u = u << 16; return v.f;
}
__device__ __forceinline__ float bfhi(unsigned u) {   // high bf16 of a u32
    union { unsigned u; float f; } v; v.u = u & 0xffff0000u; return v.f;
}

// ---------------------------------------------------------------- int histogram (degree)
__global__ __launch_bounds__(256) void hist_kernel(const int* __restrict__ idxs,
                                                   int* __restrict__ cnt, int n) {
    int i = blockIdx.x * blockDim.x + threadIdx.x;
    if (i < n) atomicAdd(&cnt[idxs[i]], 1);
}

// ---------------------------------------------------------------- exclusive scan (1024/block)
__global__ __launch_bounds__(256) void scan_block(const int* __restrict__ deg,
                                                  int* __restrict__ out,
                                                  int* __restrict__ bsum, int n) {
    __shared__ int ts[256];
    const int t = threadIdx.x;
    const int base = blockIdx.x * 1024 + t * 4;
    int4 v = make_int4(0, 0, 0, 0);
    if (base + 3 < n) v = *(const int4*)(deg + base);
    else {
        if (base + 0 < n) v.x = deg[base + 0];
        if (base + 1 < n) v.y = deg[base + 1];
        if (base + 2 < n) v.z = deg[base + 2];
        if (base + 3 < n) v.w = deg[base + 3];
    }
    int s0 = v.x, s1 = s0 + v.y, s2 = s1 + v.z, s3 = s2 + v.w;
    ts[t] = s3;
    __syncthreads();
    for (int off = 1; off < 256; off <<= 1) {
        int val = (t >= off) ? ts[t - off] : 0;
        __syncthreads();
        ts[t] += val;
        __syncthreads();
    }
    int excl = (t > 0) ? ts[t - 1] : 0;
    int4 o = make_int4(excl, excl + s0, excl + s1, excl + s2);
    if (base + 3 < n) *(int4*)(out + base) = o;
    else {
        if (base + 0 < n) out[base + 0] = o.x;
        if (base + 1 < n) out[base + 1] = o.y;
        if (base + 2 < n) out[base + 2] = o.z;
        if (base + 3 < n) out[base + 3] = o.w;
    }
    if (t == 255) bsum[blockIdx.x] = ts[255];
}

__global__ __launch_bounds__(256) void scan_sums(int* __restrict__ bsum, int nb) {
    __shared__ int s[256];
    const int t = threadIdx.x;
    s[t] = (t < nb) ? bsum[t] : 0;
    __syncthreads();
    for (int off = 1; off < 256; off <<= 1) {
        int val = (t >= off) ? s[t - off] : 0;
        __syncthreads();
        s[t] += val;
        __syncthreads();
    }
    if (t < nb) bsum[t] = (t > 0) ? s[t - 1] : 0;
}

// scan finalize + inv_deg fused
__global__ __launch_bounds__(256) void scan_add(int* __restrict__ out,
                                                const int* __restrict__ bsum,
                                                const int* __restrict__ degi,
                                                float* __restrict__ invd,
                                                int n, int total) {
    int i = blockIdx.x * 256 + threadIdx.x;
    if (i < n) {
        out[i] += bsum[i >> 10];
        invd[i] = 1.0f / (float)max(degi[i], 1);
    }
    if (i == 0) out[n] = total;
}

// ---------------------------------------------------------------- CSR scatter (by target)
__global__ __launch_bounds__(256) void scatter_kernel(const int* __restrict__ src,
                                                      const int* __restrict__ tgt,
                                                      const int* __restrict__ rowstart,
                                                      int* __restrict__ cursor,
                                                      int* __restrict__ csr, int E) {
    int e = blockIdx.x * 256 + threadIdx.x;
    if (e < E) {
        int t = tgt[e];
        int p = rowstart[t] + atomicAdd(&cursor[t], 1);
        csr[p] = src[e];
    }
}

// ---------------------------------------------------------------- graph boundaries (batch sorted)
__global__ __launch_bounds__(64) void graph_cnt_kernel(const int* __restrict__ batch,
                                                       int* __restrict__ gstart,
                                                       float* __restrict__ gcnt, int n) {
    int g = threadIdx.x;  // 0..63
    int lo = 0, hi = n;
    while (lo < hi) { int m = (lo + hi) >> 1; if (batch[m] < g) lo = m + 1; else hi = m; }
    int lb = lo;
    lo = 0; hi = n;
    while (lo < hi) { int m = (lo + hi) >> 1; if (batch[m] < g + 1) lo = m + 1; else hi = m; }
    gstart[g] = lb;
    gcnt[g] = (float)(lo - lb);
    if (g == 0) gstart[64] = n;
}

// ---------------------------------------------------------------- fp32 -> bf16 convert
__global__ __launch_bounds__(256) void conv_bf16(const float* __restrict__ in,
                                                 unsigned short* __restrict__ out, int n4) {
    int i = blockIdx.x * 256 + threadIdx.x;
    if (i < n4) {
        float4 v = *(const float4*)(in + (size_t)i * 4);
        us4 o; o.x = f2bf(v.x); o.y = f2bf(v.y); o.z = f2bf(v.z); o.w = f2bf(v.w);
        *(us4*)(out + (size_t)i * 4) = o;
    }
}

// ---------------------------------------------------------------- weight prep: fragment-ordered Wt hi/lo
// chunk c (0..63): nf=c>>3, ks=c&7 ; elem i (0..511): l=i>>3, e=i&7
// j = nf*16 + (l&15) ; k = ks*32 + (l>>4)*8 + e ; W = k<128 ? Wl[k][j] : Wr[k-128][j]
__global__ __launch_bounds__(256) void prep_w(const float* __restrict__ Wl,
                                              const float* __restrict__ Wr,
                                              unsigned short* __restrict__ outHi,
                                              unsigned short* __restrict__ outLo) {
    int id = blockIdx.x * 256 + threadIdx.x;  // 0..32767
    int c = id >> 9, i = id & 511;
    int l = i >> 3, e = i & 7;
    int j = (c >> 3) * 16 + (l & 15);
    int k = (c & 7) * 32 + ((l >> 4) << 3) + e;
    float w = (k < 128) ? Wl[k * 128 + j] : Wr[(k - 128) * 128 + j];
    unsigned short hi = f2bf(w);
    float lo = w - bf2f(hi);
    outHi[id] = hi;
    outLo[id] = f2bf(lo);
}

// ---------------------------------------------------------------- CSR mean-aggregate (bf16 in/out)
// 16 lanes per node (4 nodes/wave); 16B row loads; unroll-4 edge pipeline.
__device__ __forceinline__ void acc8(float* a, uint4 v) {
    a[0] += bflo(v.x); a[1] += bfhi(v.x);
    a[2] += bflo(v.y); a[3] += bfhi(v.y);
    a[4] += bflo(v.z); a[5] += bfhi(v.z);
    a[6] += bflo(v.w); a[7] += bfhi(v.w);
}

__global__ __launch_bounds__(256) void agg_bf16(const unsigned short* __restrict__ Xin,
                                                const int* __restrict__ csr,
                                                const int* __restrict__ rowstart,
                                                const float* __restrict__ invd,
                                                unsigned short* __restrict__ Agg, int N) {
    const int grp  = threadIdx.x >> 4;            // 0..15
    const int node = blockIdx.x * 16 + grp;
    if (node >= N) return;
    const int lane = threadIdx.x & 15;
    const int beg = rowstart[node];
    const int end = rowstart[node + 1];

    float a[8] = {0.f, 0.f, 0.f, 0.f, 0.f, 0.f, 0.f, 0.f};
    int e = beg;
    for (; e + 3 < end; e += 4) {
        int s0 = csr[e + 0];
        int s1 = csr[e + 1];
        int s2 = csr[e + 2];
        int s3 = csr[e + 3];
        uint4 v0 = *(const uint4*)(Xin + ((size_t)s0 << 7) + lane * 8);
        uint4 v1 = *(const uint4*)(Xin + ((size_t)s1 << 7) + lane * 8);
        uint4 v2 = *(const uint4*)(Xin + ((size_t)s2 << 7) + lane * 8);
        uint4 v3 = *(const uint4*)(Xin + ((size_t)s3 << 7) + lane * 8);
        acc8(a, v0); acc8(a, v1); acc8(a, v2); acc8(a, v3);
    }
    for (; e < end; ++e) {
        int s0 = csr[e];
        uint4 v0 = *(const uint4*)(Xin + ((size_t)s0 << 7) + lane * 8);
        acc8(a, v0);
    }

    float sc = invd[node];
    uint4 o;
    o.x = ((unsigned)f2bf(a[1] * sc) << 16) | (unsigned)f2bf(a[0] * sc);
    o.y = ((unsigned)f2bf(a[3] * sc) << 16) | (unsigned)f2bf(a[2] * sc);
    o.z = ((unsigned)f2bf(a[5] * sc) << 16) | (unsigned)f2bf(a[4] * sc);
    o.w = ((unsigned)f2bf(a[7] * sc) << 16) | (unsigned)f2bf(a[6] * sc);
    *(uint4*)(Agg + ((size_t)node << 7) + lane * 8) = o;
}

// ---------------------------------------------------------------- MFMA dual GEMM, split-precision W
// H[r,:] = relu( [Agg(r)|X(r)] @ (Whi+Wlo) + b ),  virtual K=256, bf16 in, bf16 out
// 512 thr = 8 waves; wave owns 32 rows x 128 cols (2 m-frags x 8 n-frags, 16x16x32 MFMA)
// W-hi staged ONCE (full K) in 64 KiB LDS; W-lo read per-use from global (L2-hit).
__global__ __launch_bounds__(512) void gemm_mfma(const unsigned short* __restrict__ Agg,
                                                 const unsigned short* __restrict__ Xop,
                                                 const unsigned short* __restrict__ WtHi,
                                                 const unsigned short* __restrict__ WtLo,
                                                 const float* __restrict__ bias,
                                                 unsigned short* __restrict__ Hout, int N) {
    __shared__ unsigned short wlds[64 * 512];   // 64 KiB, fragment-ordered (same linear layout as WtHi)

    const int t = threadIdx.x;
    const int wave = t >> 6;
    const int l = t & 63;
    const int rw = blockIdx.x * 256 + wave * 32;
    const int lrow = l & 15;
    const int lk = (l >> 4) << 3;

    // stage all of W-hi (64 KiB): straight vector memcpy
#pragma unroll
    for (int rep = 0; rep < 8; ++rep) {
        int e = rep * 4096 + t * 8;
        *(short8v*)&wlds[e] = *(const short8v*)(WtHi + e);
    }

    f32x4 acc[2][8];
#pragma unroll
    for (int m = 0; m < 2; ++m)
#pragma unroll
        for (int nf = 0; nf < 8; ++nf) acc[m][nf] = (f32x4)(0.f);

    __syncthreads();

    for (int khalf = 0; khalf < 2; ++khalf) {
        const unsigned short* Asrc = khalf ? Xop : Agg;
#pragma unroll
        for (int ks4 = 0; ks4 < 4; ++ks4) {
            short8v af[2];
#pragma unroll
            for (int m = 0; m < 2; ++m) {
                int row = rw + m * 16 + lrow;
                if (row >= N) row = N - 1;  // clamp: only pollutes discarded rows
                af[m] = *(const short8v*)(Asrc + ((size_t)row << 7) + ks4 * 32 + lk);
            }
#pragma unroll
            for (int nf = 0; nf < 8; ++nf) {
                int gc = nf * 8 + khalf * 4 + ks4;
                short8v bh = *(const short8v*)&wlds[gc * 512 + l * 8];
                short8v bl = *(const short8v*)(WtLo + gc * 512 + l * 8);
#pragma unroll
                for (int m = 0; m < 2; ++m) {
                    acc[m][nf] = __builtin_amdgcn_mfma_f32_16x16x32_bf16(af[m], bh, acc[m][nf], 0, 0, 0);
                    acc[m][nf] = __builtin_amdgcn_mfma_f32_16x16x32_bf16(af[m], bl, acc[m][nf], 0, 0, 0);
                }
            }
        }
    }

    // epilogue: D[row=(l>>4)*4+r][col=l&15] per frag ; bias + relu + bf16 store
    const int rbase = (l >> 4) << 2;
#pragma unroll
    for (int nf = 0; nf < 8; ++nf) {
        float bj = bias[nf * 16 + (l & 15)];
#pragma unroll
        for (int m = 0; m < 2; ++m) {
#pragma unroll
            for (int r = 0; r < 4; ++r) {
                int row = rw + m * 16 + rbase + r;
                if (row < N) {
                    float v = fmaxf(acc[m][nf][r] + bj, 0.f);
                    Hout[((size_t)row << 7) + nf * 16 + (l & 15)] = f2bf(v);
                }
            }
        }
    }
}

// ---------------------------------------------------------------- segment-mean pool of agg3 & h2
__global__ __launch_bounds__(256) void pool_kernel(const unsigned short* __restrict__ A3,
                                                   const unsigned short* __restrict__ H2,
                                                   const int* __restrict__ gstart,
                                                   float* __restrict__ pa,
                                                   float* __restrict__ ph) {
    int g = blockIdx.x >> 2, q = blockIdx.x & 3;
    int s = gstart[g], e = gstart[g + 1];
    int len = e - s;
    int cs = s + (len * q) / 4;
    int ce = s + (len * (q + 1)) / 4;
    int t = threadIdx.x;
    int cp = t & 63;   // column pair
    int rp = t >> 6;   // 0..3 row phase
    float sa0 = 0, sa1 = 0, sh0 = 0, sh1 = 0;
    for (int r = cs + rp; r < ce; r += 4) {
        unsigned ua = *(const unsigned*)(A3 + ((size_t)r << 7) + cp * 2);
        unsigned uh = *(const unsigned*)(H2 + ((size_t)r << 7) + cp * 2);
        sa0 += bflo(ua); sa1 += bfhi(ua);
        sh0 += bflo(uh); sh1 += bfhi(uh);
    }
    __shared__ float red[4][4][64];
    red[rp][0][cp] = sa0; red[rp][1][cp] = sa1;
    red[rp][2][cp] = sh0; red[rp][3][cp] = sh1;
    __syncthreads();
    if (rp == 0) {
        float ra0 = red[0][0][cp] + red[1][0][cp] + red[2][0][cp] + red[3][0][cp];
        float ra1 = red[0][1][cp] + red[1][1][cp] + red[2][1][cp] + red[3][1][cp];
        float rh0 = red[0][2][cp] + red[1][2][cp] + red[2][2][cp] + red[3][2][cp];
        float rh1 = red[0][3][cp] + red[1][3][cp] + red[2][3][cp] + red[3][3][cp];
        unsafeAtomicAdd(&pa[g * 128 + cp * 2 + 0], ra0);
        unsafeAtomicAdd(&pa[g * 128 + cp * 2 + 1], ra1);
        unsafeAtomicAdd(&ph[g * 128 + cp * 2 + 0], rh0);
        unsafeAtomicAdd(&ph[g * 128 + cp * 2 + 1], rh1);
    }
}

// ---------------------------------------------------------------- fused layer3 + readout (fp32)
__global__ __launch_bounds__(128) void final_fused(const float* __restrict__ pa,
                                                   const float* __restrict__ ph,
                                                   const float* __restrict__ gcnt,
                                                   const float* __restrict__ W3l,
                                                   const float* __restrict__ W3r,
                                                   const float* __restrict__ b3,
                                                   const float* __restrict__ Wout,
                                                   const float* __restrict__ bout,
                                                   float* __restrict__ out) {
    __shared__ float sA[FDIM], sH[FDIM], sT[FDIM];
    int g = blockIdx.x;
    int j = threadIdx.x;
    float inv = 1.0f / fmaxf(gcnt[g], 1.0f);
    sA[j] = pa[g * FDIM + j] * inv;
    sH[j] = ph[g * FDIM + j] * inv;
    __syncthreads();
    float acc = b3[j];
    for (int c = 0; c < FDIM; ++c)
        acc += sA[c] * W3l[c * FDIM + j] + sH[c] * W3r[c * FDIM + j];
    sT[j] = acc;   // no relu on layer 3
    __syncthreads();
    if (j < 10) {
        float o = bout[j];
        for (int c = 0; c < FDIM; ++c) o += sT[c] * Wout[c * 10 + j];
        out[g * 10 + j] = o;
    }
}

extern "C" void kernel_launch(void* const* d_in, const int* in_sizes, int n_in,
                              void* d_out, int out_size, void* d_ws, size_t ws_size,
                              hipStream_t stream) {
    const float* x     = (const float*)d_in[0];
    const int*   edge  = (const int*)d_in[1];
    const int*   batch = (const int*)d_in[2];
    const float* W1l = (const float*)d_in[3];
    const float* b1  = (const float*)d_in[4];
    const float* W1r = (const float*)d_in[5];
    const float* W2l = (const float*)d_in[6];
    const float* b2  = (const float*)d_in[7];
    const float* W2r = (const float*)d_in[8];
    const float* W3l = (const float*)d_in[9];
    const float* b3  = (const float*)d_in[10];
    const float* W3r = (const float*)d_in[11];
    const float* Wout = (const float*)d_in[12];
    const float* bout = (const float*)d_in[13];
    float* out = (float*)d_out;

    const int N = N_NODES_C;
    const int E = in_sizes[1] / 2;
    const int* src = edge;
    const int* tgt = edge + E;

    // ---- workspace layout
    char* ws = (char*)d_ws;
    size_t off = 0;
    auto carve = [&](size_t bytes) { char* p = ws + off; off += (bytes + 255) & ~(size_t)255; return p; };
    int*   degi = (int*)carve((size_t)N * 4);
    int*   rs   = (int*)carve((size_t)(N + 1) * 4);
    int*   cur  = (int*)carve((size_t)N * 4);
    int*   bsum = (int*)carve(1024);
    float* invd = (float*)carve((size_t)N * 4);
    int*   gstart = (int*)carve(65 * 4);
    float* gcnt = (float*)carve(64 * 4);
    float* pa   = (float*)carve((size_t)N_GRAPHS_C * FDIM * 4);
    float* ph   = (float*)carve((size_t)N_GRAPHS_C * FDIM * 4);
    unsigned short* wt1hi = (unsigned short*)carve(32768 * 2);
    unsigned short* wt1lo = (unsigned short*)carve(32768 * 2);
    unsigned short* wt2hi = (unsigned short*)carve(32768 * 2);
    unsigned short* wt2lo = (unsigned short*)carve(32768 * 2);
    int*   csr  = (int*)carve((size_t)E * 4);
    unsigned short* B0 = (unsigned short*)carve((size_t)N * FDIM * 2);
    unsigned short* B1 = (unsigned short*)carve((size_t)N * FDIM * 2);
    unsigned short* B2 = (unsigned short*)carve((size_t)N * FDIM * 2);

    // ---- zero init
    hipMemsetAsync(degi, 0, (size_t)N * 4, stream);
    hipMemsetAsync(cur, 0, (size_t)N * 4, stream);
    hipMemsetAsync(pa, 0, (size_t)N_GRAPHS_C * FDIM * 4, stream);
    hipMemsetAsync(ph, 0, (size_t)N_GRAPHS_C * FDIM * 4, stream);

    // ---- CSR build + degree
    hist_kernel<<<(E + 255) / 256, 256, 0, stream>>>(tgt, degi, E);
    const int NB = (N + 1023) / 1024;
    scan_block<<<NB, 256, 0, stream>>>(degi, rs, bsum, N);
    scan_sums<<<1, 256, 0, stream>>>(bsum, NB);
    scan_add<<<(N + 255) / 256, 256, 0, stream>>>(rs, bsum, degi, invd, N, E);
    graph_cnt_kernel<<<1, 64, 0, stream>>>(batch, gstart, gcnt, N);
    scatter_kernel<<<(E + 255) / 256, 256, 0, stream>>>(src, tgt, rs, cur, csr, E);

    // ---- conversions / weight prep
    conv_bf16<<<(N * FDIM / 4 + 255) / 256, 256, 0, stream>>>(x, B0, N * FDIM / 4);
    prep_w<<<128, 256, 0, stream>>>(W1l, W1r, wt1hi, wt1lo);
    prep_w<<<128, 256, 0, stream>>>(W2l, W2r, wt2hi, wt2lo);

    const int aggGrid = (N + 15) / 16;
    const int gemmGrid = (N + 255) / 256;

    // ---- layer 1: agg1 -> B1 ; h1 = relu([B1|B0]@Wt1+b1) -> B2
    agg_bf16<<<aggGrid, 256, 0, stream>>>(B0, csr, rs, invd, B1, N);
    gemm_mfma<<<gemmGrid, 512, 0, stream>>>(B1, B0, wt1hi, wt1lo, b1, B2, N);

    // ---- layer 2: agg2 -> B1 ; h2 = relu([B1|B2]@Wt2+b2) -> B0
    agg_bf16<<<aggGrid, 256, 0, stream>>>(B2, csr, rs, invd, B1, N);
    gemm_mfma<<<gemmGrid, 512, 0, stream>>>(B1, B2, wt2hi, wt2lo, b2, B0, N);

    // ---- layer 3 folded through pooling: agg3 -> B1 ; pool agg3 & h2
    agg_bf16<<<aggGrid, 256, 0, stream>>>(B0, csr, rs, invd, B1, N);
    pool_kernel<<<N_GRAPHS_C * 4, 256, 0, stream>>>(B1, B0, gstart, pa, ph);

    // ---- layer-3 GEMM (64 rows) + readout, full fp32
    final_fused<<<N_GRAPHS_C, 128, 0, stream>>>(pa, ph, gcnt, W3l, W3r, b3, Wout, bout, out);
}

// Round 5
// 291.988 us; speedup vs baseline: 14.6317x; 1.2154x over previous
//
#include <hip/hip_runtime.h>
#include <hip/hip_bf16.h>

#define N_NODES_C 100000
#define N_GRAPHS_C 64
#define FDIM 128

typedef _Float16 half8v __attribute__((ext_vector_type(8)));
typedef __attribute__((ext_vector_type(4))) float f32x4;

__device__ __forceinline__ unsigned short f2h(float f) {
    union { _Float16 h; unsigned short u; } v; v.h = (_Float16)f; return v.u;
}
__device__ __forceinline__ float h2flo(unsigned u) {
    union { unsigned short s; _Float16 h; } v; v.s = (unsigned short)u; return (float)v.h;
}
__device__ __forceinline__ float h2fhi(unsigned u) {
    union { unsigned short s; _Float16 h; } v; v.s = (unsigned short)(u >> 16); return (float)v.h;
}

// ---------------------------------------------------------------- int histogram (degree)
__global__ __launch_bounds__(256) void hist_kernel(const int* __restrict__ idxs,
                                                   int* __restrict__ cnt, int n) {
    int i = blockIdx.x * blockDim.x + threadIdx.x;
    if (i < n) atomicAdd(&cnt[idxs[i]], 1);
}

// ---------------------------------------------------------------- exclusive scan (1024/block)
__global__ __launch_bounds__(256) void scan_block(const int* __restrict__ deg,
                                                  int* __restrict__ out,
                                                  int* __restrict__ bsum, int n) {
    __shared__ int ts[256];
    const int t = threadIdx.x;
    const int base = blockIdx.x * 1024 + t * 4;
    int4 v = make_int4(0, 0, 0, 0);
    if (base + 3 < n) v = *(const int4*)(deg + base);
    else {
        if (base + 0 < n) v.x = deg[base + 0];
        if (base + 1 < n) v.y = deg[base + 1];
        if (base + 2 < n) v.z = deg[base + 2];
        if (base + 3 < n) v.w = deg[base + 3];
    }
    int s0 = v.x, s1 = s0 + v.y, s2 = s1 + v.z, s3 = s2 + v.w;
    ts[t] = s3;
    __syncthreads();
    for (int off = 1; off < 256; off <<= 1) {
        int val = (t >= off) ? ts[t - off] : 0;
        __syncthreads();
        ts[t] += val;
        __syncthreads();
    }
    int excl = (t > 0) ? ts[t - 1] : 0;
    int4 o = make_int4(excl, excl + s0, excl + s1, excl + s2);
    if (base + 3 < n) *(int4*)(out + base) = o;
    else {
        if (base + 0 < n) out[base + 0] = o.x;
        if (base + 1 < n) out[base + 1] = o.y;
        if (base + 2 < n) out[base + 2] = o.z;
        if (base + 3 < n) out[base + 3] = o.w;
    }
    if (t == 255) bsum[blockIdx.x] = ts[255];
}

__global__ __launch_bounds__(256) void scan_sums(int* __restrict__ bsum, int nb) {
    __shared__ int s[256];
    const int t = threadIdx.x;
    s[t] = (t < nb) ? bsum[t] : 0;
    __syncthreads();
    for (int off = 1; off < 256; off <<= 1) {
        int val = (t >= off) ? s[t - off] : 0;
        __syncthreads();
        s[t] += val;
        __syncthreads();
    }
    if (t < nb) bsum[t] = (t > 0) ? s[t - 1] : 0;
}

// scan finalize + inv_deg fused
__global__ __launch_bounds__(256) void scan_add(int* __restrict__ out,
                                                const int* __restrict__ bsum,
                                                const int* __restrict__ degi,
                                                float* __restrict__ invd,
                                                int n, int total) {
    int i = blockIdx.x * 256 + threadIdx.x;
    if (i < n) {
        out[i] += bsum[i >> 10];
        invd[i] = 1.0f / (float)max(degi[i], 1);
    }
    if (i == 0) out[n] = total;
}

// ---------------------------------------------------------------- CSR scatter (by target)
__global__ __launch_bounds__(256) void scatter_kernel(const int* __restrict__ src,
                                                      const int* __restrict__ tgt,
                                                      const int* __restrict__ rowstart,
                                                      int* __restrict__ cursor,
                                                      int* __restrict__ csr, int E) {
    int e = blockIdx.x * 256 + threadIdx.x;
    if (e < E) {
        int t = tgt[e];
        int p = rowstart[t] + atomicAdd(&cursor[t], 1);
        csr[p] = src[e];
    }
}

// ---------------------------------------------------------------- graph boundaries (batch sorted)
__global__ __launch_bounds__(64) void graph_cnt_kernel(const int* __restrict__ batch,
                                                       int* __restrict__ gstart,
                                                       float* __restrict__ gcnt, int n) {
    int g = threadIdx.x;  // 0..63
    int lo = 0, hi = n;
    while (lo < hi) { int m = (lo + hi) >> 1; if (batch[m] < g) lo = m + 1; else hi = m; }
    int lb = lo;
    lo = 0; hi = n;
    while (lo < hi) { int m = (lo + hi) >> 1; if (batch[m] < g + 1) lo = m + 1; else hi = m; }
    gstart[g] = lb;
    gcnt[g] = (float)(lo - lb);
    if (g == 0) gstart[64] = n;
}

// ---------------------------------------------------------------- fp32 -> fp16 convert (8/thread)
__global__ __launch_bounds__(256) void conv_f16(const float* __restrict__ in,
                                                unsigned short* __restrict__ out, int n8) {
    int i = blockIdx.x * 256 + threadIdx.x;
    if (i < n8) {
        float4 v0 = *(const float4*)(in + (size_t)i * 8);
        float4 v1 = *(const float4*)(in + (size_t)i * 8 + 4);
        half8v o;
        o[0] = (_Float16)v0.x; o[1] = (_Float16)v0.y; o[2] = (_Float16)v0.z; o[3] = (_Float16)v0.w;
        o[4] = (_Float16)v1.x; o[5] = (_Float16)v1.y; o[6] = (_Float16)v1.z; o[7] = (_Float16)v1.w;
        *(half8v*)(out + (size_t)i * 8) = o;
    }
}

// ---------------------------------------------------------------- weight prep: fragment-ordered fp16
// chunk c (0..63): khalf=c>>5, nf=(c>>2)&7, ks4=c&3 ; elem i (0..511): l=i>>3, e=i&7
// j = nf*16 + (l&15) ; k = khalf*128 + ks4*32 + (l>>4)*8 + e
__global__ __launch_bounds__(256) void prep_w(const float* __restrict__ Wl,
                                              const float* __restrict__ Wr,
                                              unsigned short* __restrict__ outW) {
    int id = blockIdx.x * 256 + threadIdx.x;  // 0..32767
    int c = id >> 9, i = id & 511;
    int l = i >> 3, e = i & 7;
    int khalf = c >> 5, nf = (c >> 2) & 7, ks4 = c & 3;
    int j = nf * 16 + (l & 15);
    int k = khalf * 128 + ks4 * 32 + ((l >> 4) << 3) + e;
    float w = (k < 128) ? Wl[k * 128 + j] : Wr[(k - 128) * 128 + j];
    outW[id] = f2h(w);
}

// ---------------------------------------------------------------- CSR mean-aggregate (fp16 in/out)
// 16 lanes per node (4 nodes/wave); 16B row loads; unroll-4 edge pipeline.
__device__ __forceinline__ void acc8h(float* a, half8v v) {
#pragma unroll
    for (int j = 0; j < 8; ++j) a[j] += (float)v[j];
}

__global__ __launch_bounds__(256) void agg_f16(const unsigned short* __restrict__ Xin,
                                               const int* __restrict__ csr,
                                               const int* __restrict__ rowstart,
                                               const float* __restrict__ invd,
                                               unsigned short* __restrict__ Agg, int N) {
    const int grp  = threadIdx.x >> 4;            // 0..15
    const int node = blockIdx.x * 16 + grp;
    if (node >= N) return;
    const int lane = threadIdx.x & 15;
    const int beg = rowstart[node];
    const int end = rowstart[node + 1];

    float a[8] = {0.f, 0.f, 0.f, 0.f, 0.f, 0.f, 0.f, 0.f};
    int e = beg;
    for (; e + 3 < end; e += 4) {
        int s0 = csr[e + 0];
        int s1 = csr[e + 1];
        int s2 = csr[e + 2];
        int s3 = csr[e + 3];
        half8v v0 = *(const half8v*)(Xin + ((size_t)s0 << 7) + lane * 8);
        half8v v1 = *(const half8v*)(Xin + ((size_t)s1 << 7) + lane * 8);
        half8v v2 = *(const half8v*)(Xin + ((size_t)s2 << 7) + lane * 8);
        half8v v3 = *(const half8v*)(Xin + ((size_t)s3 << 7) + lane * 8);
        acc8h(a, v0); acc8h(a, v1); acc8h(a, v2); acc8h(a, v3);
    }
    for (; e < end; ++e) {
        int s0 = csr[e];
        half8v v0 = *(const half8v*)(Xin + ((size_t)s0 << 7) + lane * 8);
        acc8h(a, v0);
    }

    float sc = invd[node];
    half8v o;
#pragma unroll
    for (int j = 0; j < 8; ++j) o[j] = (_Float16)(a[j] * sc);
    *(half8v*)(Agg + ((size_t)node << 7) + lane * 8) = o;
}

// ---------------------------------------------------------------- MFMA dual GEMM (fp16)
// H[r,:] = relu( [Agg(r)|X(r)] @ W + b ),  virtual K=256, fp16 in, fp16 out
// 256 thr = 4 waves; wave owns 32 rows x 128 cols (2 m-frags x 8 n-frags, 16x16x32 f16 MFMA)
// W staged per-khalf in 32 KiB LDS (linear memcpy; prep_w is khalf-major).
// SWAPPED operand order: acc = mfma(Wfrag, Afrag) => D^T: lane holds one node-row,
// 4 consecutive j-cols in regs -> 8B packed stores (no write amplification).
__global__ __launch_bounds__(256) void gemm_mfma(const unsigned short* __restrict__ Agg,
                                                 const unsigned short* __restrict__ Xop,
                                                 const unsigned short* __restrict__ WtF,
                                                 const float* __restrict__ bias,
                                                 unsigned short* __restrict__ Hout, int N) {
    __shared__ unsigned short wlds[32 * 512];   // 32 KiB: one khalf, fragment-ordered

    const int t = threadIdx.x;
    const int wave = t >> 6;
    const int l = t & 63;
    const int rw = blockIdx.x * 128 + wave * 32;
    const int lrow = l & 15;
    const int lk = (l >> 4) << 3;

    f32x4 acc[2][8];
#pragma unroll
    for (int m = 0; m < 2; ++m)
#pragma unroll
        for (int nf = 0; nf < 8; ++nf) acc[m][nf] = (f32x4)(0.f);

    for (int khalf = 0; khalf < 2; ++khalf) {
        if (khalf) __syncthreads();   // previous compute done before overwrite
        // stage this khalf's W: linear 32 KiB memcpy
#pragma unroll
        for (int rep = 0; rep < 8; ++rep) {
            int e = rep * 2048 + t * 8;
            *(half8v*)&wlds[e] = *(const half8v*)(WtF + khalf * 16384 + e);
        }
        __syncthreads();

        const unsigned short* Asrc = khalf ? Xop : Agg;
#pragma unroll
        for (int ks4 = 0; ks4 < 4; ++ks4) {
            half8v af[2];
#pragma unroll
            for (int m = 0; m < 2; ++m) {
                int row = rw + m * 16 + lrow;
                if (row >= N) row = N - 1;  // clamp: only pollutes discarded rows
                af[m] = *(const half8v*)(Asrc + ((size_t)row << 7) + ks4 * 32 + lk);
            }
#pragma unroll
            for (int nf = 0; nf < 8; ++nf) {
                half8v bh = *(const half8v*)&wlds[(nf * 4 + ks4) * 512 + l * 8];
#pragma unroll
                for (int m = 0; m < 2; ++m) {
                    // swapped: D^T fragments
                    acc[m][nf] = __builtin_amdgcn_mfma_f32_16x16x32_f16(bh, af[m], acc[m][nf], 0, 0, 0);
                }
            }
        }
    }

    // epilogue: lane holds node row = rw + m*16 + (l&15); j = nf*16 + (l>>4)*4 + r
    const int jb = (l >> 4) << 2;
#pragma unroll
    for (int nf = 0; nf < 8; ++nf) {
        float4 bv = *(const float4*)&bias[nf * 16 + jb];
#pragma unroll
        for (int m = 0; m < 2; ++m) {
            int row = rw + m * 16 + (l & 15);
            if (row < N) {
                unsigned short h0 = f2h(fmaxf(acc[m][nf][0] + bv.x, 0.f));
                unsigned short h1 = f2h(fmaxf(acc[m][nf][1] + bv.y, 0.f));
                unsigned short h2 = f2h(fmaxf(acc[m][nf][2] + bv.z, 0.f));
                unsigned short h3 = f2h(fmaxf(acc[m][nf][3] + bv.w, 0.f));
                uint2 st;
                st.x = (unsigned)h0 | ((unsigned)h1 << 16);
                st.y = (unsigned)h2 | ((unsigned)h3 << 16);
                *(uint2*)(Hout + ((size_t)row << 7) + nf * 16 + jb) = st;
            }
        }
    }
}

// ---------------------------------------------------------------- segment-mean pool of agg3 & h2
__global__ __launch_bounds__(256) void pool_kernel(const unsigned short* __restrict__ A3,
                                                   const unsigned short* __restrict__ H2,
                                                   const int* __restrict__ gstart,
                                                   float* __restrict__ pa,
                                                   float* __restrict__ ph) {
    int g = blockIdx.x >> 2, q = blockIdx.x & 3;
    int s = gstart[g], e = gstart[g + 1];
    int len = e - s;
    int cs = s + (len * q) / 4;
    int ce = s + (len * (q + 1)) / 4;
    int t = threadIdx.x;
    int cp = t & 63;   // column pair
    int rp = t >> 6;   // 0..3 row phase
    float sa0 = 0, sa1 = 0, sh0 = 0, sh1 = 0;
    for (int r = cs + rp; r < ce; r += 4) {
        unsigned ua = *(const unsigned*)(A3 + ((size_t)r << 7) + cp * 2);
        unsigned uh = *(const unsigned*)(H2 + ((size_t)r << 7) + cp * 2);
        sa0 += h2flo(ua); sa1 += h2fhi(ua);
        sh0 += h2flo(uh); sh1 += h2fhi(uh);
    }
    __shared__ float red[4][4][64];
    red[rp][0][cp] = sa0; red[rp][1][cp] = sa1;
    red[rp][2][cp] = sh0; red[rp][3][cp] = sh1;
    __syncthreads();
    if (rp == 0) {
        float ra0 = red[0][0][cp] + red[1][0][cp] + red[2][0][cp] + red[3][0][cp];
        float ra1 = red[0][1][cp] + red[1][1][cp] + red[2][1][cp] + red[3][1][cp];
        float rh0 = red[0][2][cp] + red[1][2][cp] + red[2][2][cp] + red[3][2][cp];
        float rh1 = red[0][3][cp] + red[1][3][cp] + red[2][3][cp] + red[3][3][cp];
        unsafeAtomicAdd(&pa[g * 128 + cp * 2 + 0], ra0);
        unsafeAtomicAdd(&pa[g * 128 + cp * 2 + 1], ra1);
        unsafeAtomicAdd(&ph[g * 128 + cp * 2 + 0], rh0);
        unsafeAtomicAdd(&ph[g * 128 + cp * 2 + 1], rh1);
    }
}

// ---------------------------------------------------------------- fused layer3 + readout (fp32)
__global__ __launch_bounds__(128) void final_fused(const float* __restrict__ pa,
                                                   const float* __restrict__ ph,
                                                   const float* __restrict__ gcnt,
                                                   const float* __restrict__ W3l,
                                                   const float* __restrict__ W3r,
                                                   const float* __restrict__ b3,
                                                   const float* __restrict__ Wout,
                                                   const float* __restrict__ bout,
                                                   float* __restrict__ out) {
    __shared__ float sA[FDIM], sH[FDIM], sT[FDIM];
    int g = blockIdx.x;
    int j = threadIdx.x;
    float inv = 1.0f / fmaxf(gcnt[g], 1.0f);
    sA[j] = pa[g * FDIM + j] * inv;
    sH[j] = ph[g * FDIM + j] * inv;
    __syncthreads();
    float acc = b3[j];
    for (int c = 0; c < FDIM; ++c)
        acc += sA[c] * W3l[c * FDIM + j] + sH[c] * W3r[c * FDIM + j];
    sT[j] = acc;   // no relu on layer 3
    __syncthreads();
    if (j < 10) {
        float o = bout[j];
        for (int c = 0; c < FDIM; ++c) o += sT[c] * Wout[c * 10 + j];
        out[g * 10 + j] = o;
    }
}

extern "C" void kernel_launch(void* const* d_in, const int* in_sizes, int n_in,
                              void* d_out, int out_size, void* d_ws, size_t ws_size,
                              hipStream_t stream) {
    const float* x     = (const float*)d_in[0];
    const int*   edge  = (const int*)d_in[1];
    const int*   batch = (const int*)d_in[2];
    const float* W1l = (const float*)d_in[3];
    const float* b1  = (const float*)d_in[4];
    const float* W1r = (const float*)d_in[5];
    const float* W2l = (const float*)d_in[6];
    const float* b2  = (const float*)d_in[7];
    const float* W2r = (const float*)d_in[8];
    const float* W3l = (const float*)d_in[9];
    const float* b3  = (const float*)d_in[10];
    const float* W3r = (const float*)d_in[11];
    const float* Wout = (const float*)d_in[12];
    const float* bout = (const float*)d_in[13];
    float* out = (float*)d_out;

    const int N = N_NODES_C;
    const int E = in_sizes[1] / 2;
    const int* src = edge;
    const int* tgt = edge + E;

    // ---- workspace layout
    char* ws = (char*)d_ws;
    size_t off = 0;
    auto carve = [&](size_t bytes) { char* p = ws + off; off += (bytes + 255) & ~(size_t)255; return p; };
    int*   degi = (int*)carve((size_t)N * 4);
    int*   rs   = (int*)carve((size_t)(N + 1) * 4);
    int*   cur  = (int*)carve((size_t)N * 4);
    int*   bsum = (int*)carve(1024);
    float* invd = (float*)carve((size_t)N * 4);
    int*   gstart = (int*)carve(65 * 4);
    float* gcnt = (float*)carve(64 * 4);
    float* pa   = (float*)carve((size_t)N_GRAPHS_C * FDIM * 4);
    float* ph   = (float*)carve((size_t)N_GRAPHS_C * FDIM * 4);
    unsigned short* wt1 = (unsigned short*)carve(32768 * 2);
    unsigned short* wt2 = (unsigned short*)carve(32768 * 2);
    int*   csr  = (int*)carve((size_t)E * 4);
    unsigned short* B0 = (unsigned short*)carve((size_t)N * FDIM * 2);
    unsigned short* B1 = (unsigned short*)carve((size_t)N * FDIM * 2);
    unsigned short* B2 = (unsigned short*)carve((size_t)N * FDIM * 2);

    // ---- zero init
    hipMemsetAsync(degi, 0, (size_t)N * 4, stream);
    hipMemsetAsync(cur, 0, (size_t)N * 4, stream);
    hipMemsetAsync(pa, 0, (size_t)N_GRAPHS_C * FDIM * 4, stream);
    hipMemsetAsync(ph, 0, (size_t)N_GRAPHS_C * FDIM * 4, stream);

    // ---- CSR build + degree
    hist_kernel<<<(E + 255) / 256, 256, 0, stream>>>(tgt, degi, E);
    const int NB = (N + 1023) / 1024;
    scan_block<<<NB, 256, 0, stream>>>(degi, rs, bsum, N);
    scan_sums<<<1, 256, 0, stream>>>(bsum, NB);
    scan_add<<<(N + 255) / 256, 256, 0, stream>>>(rs, bsum, degi, invd, N, E);
    graph_cnt_kernel<<<1, 64, 0, stream>>>(batch, gstart, gcnt, N);
    scatter_kernel<<<(E + 255) / 256, 256, 0, stream>>>(src, tgt, rs, cur, csr, E);

    // ---- conversions / weight prep
    conv_f16<<<(N * FDIM / 8 + 255) / 256, 256, 0, stream>>>(x, B0, N * FDIM / 8);
    prep_w<<<128, 256, 0, stream>>>(W1l, W1r, wt1);
    prep_w<<<128, 256, 0, stream>>>(W2l, W2r, wt2);

    const int aggGrid = (N + 15) / 16;
    const int gemmGrid = (N + 127) / 128;

    // ---- layer 1: agg1 -> B1 ; h1 = relu([B1|B0]@W1+b1) -> B2
    agg_f16<<<aggGrid, 256, 0, stream>>>(B0, csr, rs, invd, B1, N);
    gemm_mfma<<<gemmGrid, 256, 0, stream>>>(B1, B0, wt1, b1, B2, N);

    // ---- layer 2: agg2 -> B1 ; h2 = relu([B1|B2]@W2+b2) -> B0
    agg_f16<<<aggGrid, 256, 0, stream>>>(B2, csr, rs, invd, B1, N);
    gemm_mfma<<<gemmGrid, 256, 0, stream>>>(B1, B2, wt2, b2, B0, N);

    // ---- layer 3 folded through pooling: agg3 -> B1 ; pool agg3 & h2
    agg_f16<<<aggGrid, 256, 0, stream>>>(B0, csr, rs, invd, B1, N);
    pool_kernel<<<N_GRAPHS_C * 4, 256, 0, stream>>>(B1, B0, gstart, pa, ph);

    // ---- layer-3 GEMM (64 rows) + readout, full fp32
    final_fused<<<N_GRAPHS_C, 128, 0, stream>>>(pa, ph, gcnt, W3l, W3r, b3, Wout, bout, out);
}